// Round 11
// baseline (388.189 us; speedup 1.0000x reference)
//
#include <hip/hip_runtime.h>

#define NN 100000
#define EE 1600000
#define NBUCK ((NN + 255) >> 8)        // 391
#define CHUNK 8192
#define NPBLK ((EE + CHUNK - 1) / CHUNK) // 196

typedef __attribute__((ext_vector_type(8))) short short8_t;
typedef __attribute__((ext_vector_type(4))) float f32x4;

static __device__ inline unsigned short f2bf(float f) {
    unsigned int u = __float_as_uint(f);
    u += 0x7FFFu + ((u >> 16) & 1u);
    return (unsigned short)(u >> 16);
}
static __device__ inline float bf2f(unsigned short h) {
    return __uint_as_float(((unsigned int)h) << 16);
}
static __device__ inline float u2f(unsigned int u) { return __uint_as_float(u); }

// ================= CSR build: contention-free radix partition =================
__global__ __launch_bounds__(256) void part_count(const int* __restrict__ ei,
                                                  int* __restrict__ cnt) {
    __shared__ int h[NBUCK];
    for (int i = threadIdx.x; i < NBUCK; i += 256) h[i] = 0;
    __syncthreads();
    int e0 = blockIdx.x * CHUNK;
    int e1 = e0 + CHUNK; if (e1 > EE) e1 = EE;
    for (int e = e0 + threadIdx.x; e < e1; e += 256)
        atomicAdd(&h[ei[EE + e] >> 8], 1);
    __syncthreads();
    for (int i = threadIdx.x; i < NBUCK; i += 256)
        cnt[blockIdx.x * NBUCK + i] = h[i];
}

__global__ void part_scan(const int* __restrict__ cnt, int* __restrict__ base,
                          int* __restrict__ bbase) {
    __shared__ int tot[512];
    int b = threadIdx.x;
    int t = 0;
    if (b < NBUCK)
        for (int k = 0; k < NPBLK; ++k) t += cnt[k * NBUCK + b];
    tot[b] = t;
    __syncthreads();
    for (int off = 1; off < 512; off <<= 1) {
        int u = (b >= off) ? tot[b - off] : 0;
        __syncthreads();
        tot[b] += u;
        __syncthreads();
    }
    int excl = tot[b] - t;
    if (b < NBUCK) {
        bbase[b] = excl;
        int run = excl;
        for (int k = 0; k < NPBLK; ++k) {
            base[k * NBUCK + b] = run;
            run += cnt[k * NBUCK + b];
        }
    }
    if (b == 0) bbase[NBUCK] = EE;
}

__global__ __launch_bounds__(256) void part_scatter(const int* __restrict__ ei,
                                                    const int* __restrict__ base,
                                                    unsigned int* __restrict__ bbuf) {
    __shared__ int lcur[NBUCK];
    for (int i = threadIdx.x; i < NBUCK; i += 256)
        lcur[i] = base[blockIdx.x * NBUCK + i];
    __syncthreads();
    int e0 = blockIdx.x * CHUNK;
    int e1 = e0 + CHUNK; if (e1 > EE) e1 = EE;
    for (int e = e0 + threadIdx.x; e < e1; e += 256) {
        int s = ei[e], d = ei[EE + e];
        int pos = atomicAdd(&lcur[d >> 8], 1);
        bbuf[pos] = (unsigned int)s | ((unsigned int)(d & 255) << 24);
    }
}

__global__ __launch_bounds__(256) void csr_build(const unsigned int* __restrict__ bbuf,
                                                 const int* __restrict__ bbase,
                                                 int* __restrict__ row_ptr,
                                                 int* __restrict__ col) {
    __shared__ int hist[256];
    __shared__ int sc[256];
    __shared__ int lcur[256];
    int b = blockIdx.x;
    int t = threadIdx.x;
    int n0 = b << 8;
    int nCnt = NN - n0; if (nCnt > 256) nCnt = 256;
    int es = bbase[b], ee2 = bbase[b + 1];
    hist[t] = 0;
    __syncthreads();
    for (int i = es + t; i < ee2; i += 256)
        atomicAdd(&hist[bbuf[i] >> 24], 1);
    __syncthreads();
    int v = hist[t];
    sc[t] = v;
    __syncthreads();
    for (int off = 1; off < 256; off <<= 1) {
        int u = (t >= off) ? sc[t - off] : 0;
        __syncthreads();
        sc[t] += u;
        __syncthreads();
    }
    int excl = sc[t] - v;
    if (t < nCnt) row_ptr[n0 + t] = es + excl;
    if (b == 0 && t == 0) row_ptr[NN] = EE;
    lcur[t] = excl;
    __syncthreads();
    for (int i = es + t; i < ee2; i += 256) {
        unsigned int pk = bbuf[i];
        int lpos = atomicAdd(&lcur[pk >> 24], 1);
        col[es + lpos] = (int)(pk & 0x00FFFFFFu);
    }
}

// ================= weight prep =================
__global__ void bsplit_kernel(const float* __restrict__ W, int ldw, int K, int N,
                              unsigned short* __restrict__ BThi,
                              unsigned short* __restrict__ BTlo,
                              int stride, int koff, int KPseg) {
    int k = blockIdx.x * 256 + threadIdx.x;
    int col = blockIdx.y;
    if (k >= KPseg) return;
    float v = (k < K && col < N) ? W[(size_t)k * ldw + col] : 0.f;
    unsigned short hi = f2bf(v);
    unsigned short lo = f2bf(v - bf2f(hi));
    BThi[(size_t)col * stride + koff + k] = hi;
    BTlo[(size_t)col * stride + koff + k] = lo;
}

__global__ void cvec_kernel(const float* __restrict__ b_feat,
                            const float* __restrict__ W0, float* __restrict__ cvec) {
    int j = threadIdx.x;
    float s = 0.f;
    for (int k = 0; k < 128; ++k) s += b_feat[k] * W0[(40 + k) * 128 + j];
    cvec[j] = s;
}

// ====== barrier-free LDS-free split-bf16 MFMA GEMM ======
// Each wave owns 32 rows x (NCT*16) cols independently. Fragments read directly
// from global: A row-major f32 (split on the fly) or bf16; B from pre-split
// transposed planes BT[col][K] (L2-resident). No LDS, no __syncthreads.
// COLSPLIT=2: wave wv -> rows (wv>>1)*32, cols (wv&1)*64 (NCT=4).
// COLSPLIT=1: wave wv -> rows wv*32, cols 0..NCT*16.
// Requires M % 32 == 0, KPtot % 64 == 0 (even # of 32-K steps).
template <int OUTBF16, int ABF16, int ATTN, int NCT, int COLSPLIT>
__global__ __launch_bounds__(256) void mfma_gemm_kernel(
    const void* __restrict__ A1v, int lda1, int K1, int KP1,
    const float* __restrict__ A2, int lda2, int K2,
    int M,
    const unsigned short* __restrict__ BThi, const unsigned short* __restrict__ BTlo,
    int bstride, int KPtot,
    void* __restrict__ Cout, int ldc, int Nact, const float* __restrict__ bias,
    const float* __restrict__ att_src, const float* __restrict__ att_dst,
    float* __restrict__ a_srcO, float* __restrict__ a_dstO)
{
    const int wv = (blockIdx.x * 256 + threadIdx.x) >> 6;
    const int nRowWaves = M >> 5;
    if (wv >= nRowWaves * COLSPLIT) return;
    const int lane = threadIdx.x & 63;
    const int fr = lane & 15;
    const int fslot = lane >> 4;
    const int row0 = (COLSPLIT == 2 ? (wv >> 1) : wv) * 32;
    const int cbase = (COLSPLIT == 2 ? (wv & 1) * 64 : 0);

    f32x4 acc[2][NCT];
#pragma unroll
    for (int i = 0; i < 2; ++i)
#pragma unroll
        for (int j = 0; j < NCT; ++j) acc[i][j] = (f32x4){0.f, 0.f, 0.f, 0.f};

    // B column pointers (per ct, fixed)
    const unsigned short* Bhp[NCT];
    const unsigned short* Blp[NCT];
#pragma unroll
    for (int ct = 0; ct < NCT; ++ct) {
        size_t co = (size_t)(cbase + ct * 16 + fr) * bstride;
        Bhp[ct] = BThi + co;
        Blp[ct] = BTlo + co;
    }
    // A row pointers (bf16 path)
    const unsigned short* Arow_b[2] = {nullptr, nullptr};
    if (ABF16) {
        Arow_b[0] = (const unsigned short*)A1v + (size_t)(row0 + fr) * lda1;
        Arow_b[1] = Arow_b[0] + (size_t)16 * lda1;
    }

    const short8_t zz = {0, 0, 0, 0, 0, 0, 0, 0};
    float raA[2][8], raB[2][8];
    short8_t rabA[2], rabB[2];

#define LOADA_(kk, RA, RAB) {                                             \
        if (ABF16) {                                                      \
            int gk = (kk) + fslot * 8;                                    \
            _Pragma("unroll")                                             \
            for (int rt = 0; rt < 2; ++rt)                                \
                RAB[rt] = (gk + 8 <= K1) ? *(const short8_t*)&Arow_b[rt][gk] : zz; \
        } else {                                                          \
            const float* Aseg; int kk2, Klim, ld_;                        \
            if ((kk) < KP1) { Aseg = (const float*)A1v; kk2 = (kk); Klim = K1; ld_ = lda1; } \
            else            { Aseg = A2; kk2 = (kk) - KP1; Klim = K2; ld_ = lda2; } \
            int gk = kk2 + fslot * 8;                                     \
            _Pragma("unroll")                                             \
            for (int rt = 0; rt < 2; ++rt) {                              \
                const float* p = Aseg + (size_t)(row0 + rt * 16 + fr) * ld_ + gk; \
                if (gk + 8 <= Klim) {                                     \
                    float4 v0 = *(const float4*)p;                        \
                    float4 v1 = *(const float4*)(p + 4);                  \
                    RA[rt][0] = v0.x; RA[rt][1] = v0.y; RA[rt][2] = v0.z; RA[rt][3] = v0.w; \
                    RA[rt][4] = v1.x; RA[rt][5] = v1.y; RA[rt][6] = v1.z; RA[rt][7] = v1.w; \
                } else {                                                  \
                    _Pragma("unroll")                                     \
                    for (int j_ = 0; j_ < 8; ++j_) RA[rt][j_] = 0.f;      \
                }                                                         \
            }                                                             \
        }                                                                 \
    }

#define GSTEP_(kk, RA, RAB, PREK, DOPRE, RAN, RABN) {                     \
        /* issue B loads for this k-step */                               \
        short8_t bh[NCT], bl[NCT];                                        \
        int ko_ = (kk) + fslot * 8;                                       \
        _Pragma("unroll")                                                 \
        for (int ct = 0; ct < NCT; ++ct) {                                \
            bh[ct] = *(const short8_t*)&Bhp[ct][ko_];                     \
            bl[ct] = *(const short8_t*)&Blp[ct][ko_];                     \
        }                                                                 \
        /* issue next A loads (latency hidden under convert+MFMA) */      \
        if (DOPRE) LOADA_(PREK, RAN, RABN);                               \
        /* convert current A */                                           \
        short8_t ah[2], al[2];                                            \
        if (ABF16) {                                                      \
            ah[0] = RAB[0]; ah[1] = RAB[1];                               \
        } else {                                                          \
            _Pragma("unroll")                                             \
            for (int rt = 0; rt < 2; ++rt) {                              \
                _Pragma("unroll")                                         \
                for (int j_ = 0; j_ < 8; ++j_) {                          \
                    unsigned short hi_ = f2bf(RA[rt][j_]);                \
                    ah[rt][j_] = (short)hi_;                              \
                    al[rt][j_] = (short)f2bf(RA[rt][j_] - bf2f(hi_));     \
                }                                                         \
            }                                                             \
        }                                                                 \
        _Pragma("unroll")                                                 \
        for (int rt = 0; rt < 2; ++rt) {                                  \
            _Pragma("unroll")                                             \
            for (int ct = 0; ct < NCT; ++ct) {                            \
                acc[rt][ct] = __builtin_amdgcn_mfma_f32_16x16x32_bf16(ah[rt], bh[ct], acc[rt][ct], 0, 0, 0); \
                acc[rt][ct] = __builtin_amdgcn_mfma_f32_16x16x32_bf16(ah[rt], bl[ct], acc[rt][ct], 0, 0, 0); \
                if (!ABF16)                                               \
                    acc[rt][ct] = __builtin_amdgcn_mfma_f32_16x16x32_bf16(al[rt], bh[ct], acc[rt][ct], 0, 0, 0); \
            }                                                             \
        }                                                                 \
    }

    LOADA_(0, raA, rabA);
    for (int k0 = 0; k0 < KPtot; k0 += 64) {
        GSTEP_(k0, raA, rabA, k0 + 32, 1, raB, rabB);
        GSTEP_(k0 + 32, raB, rabB, k0 + 64, (k0 + 64 < KPtot), raA, rabA);
    }
#undef LOADA_
#undef GSTEP_

    // ---- epilogue ----
    if (ATTN) {
        const int head = wv & 1;
#pragma unroll
        for (int rt = 0; rt < 2; ++rt) {
#pragma unroll
            for (int reg = 0; reg < 4; ++reg) {
                float ps = 0.f, pd = 0.f;
#pragma unroll
                for (int ct = 0; ct < NCT; ++ct) {
                    int c = cbase + ct * 16 + fr;
                    ps += acc[rt][ct][reg] * att_src[c];
                    pd += acc[rt][ct][reg] * att_dst[c];
                }
#pragma unroll
                for (int off = 1; off < 16; off <<= 1) {
                    ps += __shfl_xor(ps, off);
                    pd += __shfl_xor(pd, off);
                }
                if (fr == 0) {
                    int r = row0 + rt * 16 + fslot * 4 + reg;
                    a_srcO[r * 2 + head] = ps;
                    a_dstO[r * 2 + head] = pd;
                }
            }
        }
    }
#pragma unroll
    for (int rt = 0; rt < 2; ++rt) {
#pragma unroll
        for (int reg = 0; reg < 4; ++reg) {
            int r = row0 + rt * 16 + fslot * 4 + reg;
#pragma unroll
            for (int ct = 0; ct < NCT; ++ct) {
                int c = cbase + ct * 16 + fr;
                float v = acc[rt][ct][reg];
                if (bias) v += bias[c];
                if (OUTBF16) {
                    ((unsigned short*)Cout)[(size_t)r * 128 + c] = f2bf(v);
                } else {
                    if (c < Nact)
                        ((float*)Cout)[(size_t)r * ldc + c] = v;
                }
            }
        }
    }
}

// ========== fused GAT aggregation: 2 nodes per wave, CSR gather ==========
// lanes 0-31 -> node 2w, lanes 32-63 -> node 2w+1. Lane l5=lane&31 owns
// channels 4*l5..+3 (8B gather/lane). Weight head for lane = l5>>4.
// Weight batches of 16 edges: l5 0-15 compute head-0 w, l5 16-31 head-1 w.
template <int RELU, int OUTBF16>
__global__ __launch_bounds__(256) void gat_agg_fused(
    const int* __restrict__ row_ptr, const int* __restrict__ col,
    const float* __restrict__ a_src, const float* __restrict__ a_dst,
    const unsigned short* __restrict__ hb,
    const float* __restrict__ bias, void* __restrict__ out)
{
    int wv = (blockIdx.x * 256 + threadIdx.x) >> 6;
    int lane = threadIdx.x & 63;
    int hl = lane >> 5;
    int l5 = lane & 31;
    int n = wv * 2 + hl;
    if (n >= NN) return;   // NN even -> wave-uniform
    int hch = l5 >> 4;
    const uint2* h4 = (const uint2*)hb;

    float2 ad2 = ((const float2*)a_dst)[n];
    float adh = hch ? ad2.y : ad2.x;
    float2 as2 = ((const float2*)a_src)[n];
    float e0 = (hch ? as2.y : as2.x) + adh;
    e0 = e0 > 0.f ? e0 : 0.2f * e0;
    float w = __expf(e0);
    uint2 hv = h4[(size_t)n * 32 + l5];
    float a0 = w * u2f(hv.x << 16);
    float a1 = w * u2f(hv.x & 0xFFFF0000u);
    float a2 = w * u2f(hv.y << 16);
    float a3 = w * u2f(hv.y & 0xFFFF0000u);
    float den = w;

    int rs = row_ptr[n], re = row_ptr[n + 1];
    int deg = re - rs;
    int degO = __shfl(deg, lane ^ 32);
    int degm = deg > degO ? deg : degO;
    int nbm = (degm + 15) >> 4;

    for (int bi = 0; bi < nbm; ++bi) {
        int base = rs + bi * 16;
        int cnt = re - base;
        cnt = cnt < 0 ? 0 : (cnt > 16 ? 16 : cnt);
        int cntO = __shfl(cnt, lane ^ 32);
        int cntm = cnt > cntO ? cnt : cntO;
        int j16 = l5 & 15;
        int sL = 0;
        float wL = 0.f;
        if (j16 < cnt) {
            sL = col[base + j16];
            float2 as = ((const float2*)a_src)[sL];
            float tt = (hch ? as.y : as.x) + adh;
            tt = tt > 0.f ? tt : 0.2f * tt;
            wL = __expf(tt);
        }
        const int sb = hl << 5;             // shuffle base for this half
        const int wb = sb + (hch << 4);     // weight source group
        int i = 0;
        for (; i + 8 <= cntm; i += 8) {
            int s[8]; uint2 g[8]; float ws[8];
#pragma unroll
            for (int j = 0; j < 8; ++j) s[j] = __shfl(sL, sb + i + j);
#pragma unroll
            for (int j = 0; j < 8; ++j) g[j] = h4[(size_t)s[j] * 32 + l5];
#pragma unroll
            for (int j = 0; j < 8; ++j) ws[j] = __shfl(wL, wb + i + j);
#pragma unroll
            for (int j = 0; j < 8; ++j) {
                a0 += ws[j] * u2f(g[j].x << 16);
                a1 += ws[j] * u2f(g[j].x & 0xFFFF0000u);
                a2 += ws[j] * u2f(g[j].y << 16);
                a3 += ws[j] * u2f(g[j].y & 0xFFFF0000u);
                den += ws[j];
            }
        }
        for (; i + 4 <= cntm; i += 4) {
            int s[4]; uint2 g[4]; float ws[4];
#pragma unroll
            for (int j = 0; j < 4; ++j) s[j] = __shfl(sL, sb + i + j);
#pragma unroll
            for (int j = 0; j < 4; ++j) g[j] = h4[(size_t)s[j] * 32 + l5];
#pragma unroll
            for (int j = 0; j < 4; ++j) ws[j] = __shfl(wL, wb + i + j);
#pragma unroll
            for (int j = 0; j < 4; ++j) {
                a0 += ws[j] * u2f(g[j].x << 16);
                a1 += ws[j] * u2f(g[j].x & 0xFFFF0000u);
                a2 += ws[j] * u2f(g[j].y << 16);
                a3 += ws[j] * u2f(g[j].y & 0xFFFF0000u);
                den += ws[j];
            }
        }
        for (; i < cntm; ++i) {
            int s = __shfl(sL, sb + i);
            float ws = __shfl(wL, wb + i);
            uint2 g = h4[(size_t)s * 32 + l5];
            a0 += ws * u2f(g.x << 16);
            a1 += ws * u2f(g.x & 0xFFFF0000u);
            a2 += ws * u2f(g.y << 16);
            a3 += ws * u2f(g.y & 0xFFFF0000u);
            den += ws;
        }
    }
    float inv = 1.f / (den + 1e-16f);
    float4 b4 = ((const float4*)bias)[l5];
    float o0 = a0 * inv + b4.x;
    float o1 = a1 * inv + b4.y;
    float o2 = a2 * inv + b4.z;
    float o3 = a3 * inv + b4.w;
    if (RELU) {
        o0 = fmaxf(o0, 0.f); o1 = fmaxf(o1, 0.f);
        o2 = fmaxf(o2, 0.f); o3 = fmaxf(o3, 0.f);
    }
    if (OUTBF16) {
        uint2 pk;
        pk.x = (unsigned int)f2bf(o0) | ((unsigned int)f2bf(o1) << 16);
        pk.y = (unsigned int)f2bf(o2) | ((unsigned int)f2bf(o3) << 16);
        ((uint2*)out)[(size_t)n * 32 + l5] = pk;
    } else {
        ((float4*)out)[(size_t)n * 32 + l5] = make_float4(o0, o1, o2, o3);
    }
}

extern "C" void kernel_launch(void* const* d_in, const int* in_sizes, int n_in,
                              void* d_out, int out_size, void* d_ws, size_t ws_size,
                              hipStream_t stream) {
    const float* logits   = (const float*)d_in[0];
    const float* features = (const float*)d_in[1];
    const int*   ei       = (const int*)d_in[2];
    const float* W_feat   = (const float*)d_in[3];
    const float* b_feat   = (const float*)d_in[4];
    const float* W0       = (const float*)d_in[5];
    const float* att_src0 = (const float*)d_in[6];
    const float* att_dst0 = (const float*)d_in[7];
    const float* bias0    = (const float*)d_in[8];
    const float* W1       = (const float*)d_in[9];
    const float* att_src1 = (const float*)d_in[10];
    const float* att_dst1 = (const float*)d_in[11];
    const float* bias1    = (const float*)d_in[12];
    const float* W_out    = (const float*)d_in[13];
    const float* b_out    = (const float*)d_in[14];
    float* out = (float*)d_out;

    float* agg    = (float*)d_ws;                       // NN*128 f32 (bf16 view for L0)
    float* a_srcb = agg + (size_t)NN * 128;             // NN*2
    float* a_dstb = a_srcb + (size_t)NN * 2;            // NN*2
    float* Wc     = a_dstb + (size_t)NN * 2;            // 256*128
    float* cvec   = Wc + 256 * 128;                     // 128
    unsigned short* hbuf = (unsigned short*)(cvec + 128);      // NN*128 bf16
    unsigned short* BT0hi = hbuf + (size_t)NN * 128;    // 128*320
    unsigned short* BT0lo = BT0hi + 128 * 320;
    unsigned short* BTbhi = BT0lo + 128 * 320;          // 128*128 (W0b planes)
    unsigned short* BTblo = BTbhi + 128 * 128;
    unsigned short* BT1hi = BTblo + 128 * 128;          // 128*128
    unsigned short* BT1lo = BT1hi + 128 * 128;
    unsigned short* BTohi = BT1lo + 128 * 128;          // 128*128
    unsigned short* BTolo = BTohi + 128 * 128;
    int* row_ptr = (int*)(BTolo + 128 * 128);           // NN+1
    int* colbuf  = row_ptr + NN + 1;                    // EE
    int* cnt     = colbuf + EE;                         // NPBLK*NBUCK
    int* pbase   = cnt + NPBLK * NBUCK;                 // NPBLK*NBUCK
    int* bbase   = pbase + NPBLK * NBUCK;               // NBUCK+1
    unsigned int* bbuf = (unsigned int*)agg;            // EE u32, aliases agg
    unsigned short* aggb = (unsigned short*)agg;        // bf16 view for layer0 output

    dim3 blk(256);
    const int gemmGrid2 = ((NN / 32) * 2 + 3) / 4;      // COLSPLIT=2: 6250 waves
    const int gemmGrid1 = ((NN / 32) + 3) / 4;          // COLSPLIT=1: 3125 waves
    const int aggGrid = (NN / 2 + 3) / 4;               // 50000 waves

    // ---- CSR build ----
    part_count<<<dim3(NPBLK), blk, 0, stream>>>(ei, cnt);
    part_scan<<<dim3(1), dim3(512), 0, stream>>>(cnt, pbase, bbase);
    part_scatter<<<dim3(NPBLK), blk, 0, stream>>>(ei, pbase, bbuf);
    csr_build<<<dim3(NBUCK), blk, 0, stream>>>(bbuf, bbase, row_ptr, colbuf);

    // ---- weight prep ----
    bsplit_kernel<<<dim3(1, 128), blk, 0, stream>>>(W0, 128, 40, 128, BT0hi, BT0lo, 320, 0, 64);
    bsplit_kernel<<<dim3(1, 128), blk, 0, stream>>>(W0 + 40 * 128, 128, 128, 128, BTbhi, BTblo, 128, 0, 128);
    mfma_gemm_kernel<0, 0, 0, 4, 2><<<dim3(4), blk, 0, stream>>>(
        W_feat, 128, 128, 128, nullptr, 0, 0, 256,
        BTbhi, BTblo, 128, 128, Wc, 128, 128, nullptr,
        nullptr, nullptr, nullptr, nullptr);
    cvec_kernel<<<dim3(1), dim3(128), 0, stream>>>(b_feat, W0, cvec);
    bsplit_kernel<<<dim3(1, 128), blk, 0, stream>>>(Wc, 128, 256, 128, BT0hi, BT0lo, 320, 64, 256);
    bsplit_kernel<<<dim3(1, 128), blk, 0, stream>>>(W1, 128, 128, 128, BT1hi, BT1lo, 128, 0, 128);
    bsplit_kernel<<<dim3(1, 128), blk, 0, stream>>>(W_out, 40, 128, 40, BTohi, BTolo, 128, 0, 128);

    // ---- GAT layer 0: h0 = logits@W0a + features@Wc + cvec (attn dots fused) ----
    mfma_gemm_kernel<1, 0, 1, 4, 2><<<dim3(gemmGrid2), blk, 0, stream>>>(
        logits, 40, 40, 64, features, 256, 256, NN,
        BT0hi, BT0lo, 320, 320, hbuf, 128, 128, cvec,
        att_src0, att_dst0, a_srcb, a_dstb);
    gat_agg_fused<1, 1><<<dim3(aggGrid), blk, 0, stream>>>(
        row_ptr, colbuf, a_srcb, a_dstb, hbuf, bias0, aggb);

    // ---- GAT layer 1 (bf16 A, attn dots fused) ----
    mfma_gemm_kernel<1, 1, 1, 4, 2><<<dim3(gemmGrid2), blk, 0, stream>>>(
        aggb, 128, 128, 128, nullptr, 0, 0, NN,
        BT1hi, BT1lo, 128, 128, hbuf, 128, 128, nullptr,
        att_src1, att_dst1, a_srcb, a_dstb);
    gat_agg_fused<0, 0><<<dim3(aggGrid), blk, 0, stream>>>(
        row_ptr, colbuf, a_srcb, a_dstb, hbuf, bias1, agg);

    // ---- output projection (48 cols computed, 40 used) ----
    mfma_gemm_kernel<0, 0, 0, 3, 1><<<dim3(gemmGrid1), blk, 0, stream>>>(
        agg, 128, 128, 128, nullptr, 0, 0, NN,
        BTohi, BTolo, 128, 128, out, 40, 40, b_out,
        nullptr, nullptr, nullptr, nullptr);
}

// Round 12
// 305.483 us; speedup vs baseline: 1.2707x; 1.2707x over previous
//
#include <hip/hip_runtime.h>

#define NN 100000
#define EE 1600000
#define NBUCK ((NN + 255) >> 8)        // 391
#define CHUNK 8192
#define NPBLK ((EE + CHUNK - 1) / CHUNK) // 196

typedef __attribute__((ext_vector_type(8))) short short8_t;
typedef __attribute__((ext_vector_type(4))) float f32x4;

static __device__ inline unsigned short f2bf(float f) {
    unsigned int u = __float_as_uint(f);
    u += 0x7FFFu + ((u >> 16) & 1u);
    return (unsigned short)(u >> 16);
}
static __device__ inline float bf2f(unsigned short h) {
    return __uint_as_float(((unsigned int)h) << 16);
}
static __device__ inline float u2f(unsigned int u) { return __uint_as_float(u); }

// ================= CSR build: contention-free radix partition =================
__global__ __launch_bounds__(256) void part_count(const int* __restrict__ ei,
                                                  int* __restrict__ cnt) {
    __shared__ int h[NBUCK];
    for (int i = threadIdx.x; i < NBUCK; i += 256) h[i] = 0;
    __syncthreads();
    int e0 = blockIdx.x * CHUNK;
    int e1 = e0 + CHUNK; if (e1 > EE) e1 = EE;
    for (int e = e0 + threadIdx.x; e < e1; e += 256)
        atomicAdd(&h[ei[EE + e] >> 8], 1);
    __syncthreads();
    for (int i = threadIdx.x; i < NBUCK; i += 256)
        cnt[blockIdx.x * NBUCK + i] = h[i];
}

__global__ void part_scan(const int* __restrict__ cnt, int* __restrict__ base,
                          int* __restrict__ bbase) {
    __shared__ int tot[512];
    int b = threadIdx.x;
    int t = 0;
    if (b < NBUCK)
        for (int k = 0; k < NPBLK; ++k) t += cnt[k * NBUCK + b];
    tot[b] = t;
    __syncthreads();
    for (int off = 1; off < 512; off <<= 1) {
        int u = (b >= off) ? tot[b - off] : 0;
        __syncthreads();
        tot[b] += u;
        __syncthreads();
    }
    int excl = tot[b] - t;
    if (b < NBUCK) {
        bbase[b] = excl;
        int run = excl;
        for (int k = 0; k < NPBLK; ++k) {
            base[k * NBUCK + b] = run;
            run += cnt[k * NBUCK + b];
        }
    }
    if (b == 0) bbase[NBUCK] = EE;
}

__global__ __launch_bounds__(256) void part_scatter(const int* __restrict__ ei,
                                                    const int* __restrict__ base,
                                                    unsigned int* __restrict__ bbuf) {
    __shared__ int lcur[NBUCK];
    for (int i = threadIdx.x; i < NBUCK; i += 256)
        lcur[i] = base[blockIdx.x * NBUCK + i];
    __syncthreads();
    int e0 = blockIdx.x * CHUNK;
    int e1 = e0 + CHUNK; if (e1 > EE) e1 = EE;
    for (int e = e0 + threadIdx.x; e < e1; e += 256) {
        int s = ei[e], d = ei[EE + e];
        int pos = atomicAdd(&lcur[d >> 8], 1);
        bbuf[pos] = (unsigned int)s | ((unsigned int)(d & 255) << 24);
    }
}

__global__ __launch_bounds__(256) void csr_build(const unsigned int* __restrict__ bbuf,
                                                 const int* __restrict__ bbase,
                                                 int* __restrict__ row_ptr,
                                                 int* __restrict__ col) {
    __shared__ int hist[256];
    __shared__ int sc[256];
    __shared__ int lcur[256];
    int b = blockIdx.x;
    int t = threadIdx.x;
    int n0 = b << 8;
    int nCnt = NN - n0; if (nCnt > 256) nCnt = 256;
    int es = bbase[b], ee2 = bbase[b + 1];
    hist[t] = 0;
    __syncthreads();
    for (int i = es + t; i < ee2; i += 256)
        atomicAdd(&hist[bbuf[i] >> 24], 1);
    __syncthreads();
    int v = hist[t];
    sc[t] = v;
    __syncthreads();
    for (int off = 1; off < 256; off <<= 1) {
        int u = (t >= off) ? sc[t - off] : 0;
        __syncthreads();
        sc[t] += u;
        __syncthreads();
    }
    int excl = sc[t] - v;
    if (t < nCnt) row_ptr[n0 + t] = es + excl;
    if (b == 0 && t == 0) row_ptr[NN] = EE;
    lcur[t] = excl;
    __syncthreads();
    for (int i = es + t; i < ee2; i += 256) {
        unsigned int pk = bbuf[i];
        int lpos = atomicAdd(&lcur[pk >> 24], 1);
        col[es + lpos] = (int)(pk & 0x00FFFFFFu);
    }
}

// ================= weight prep =================
__global__ void bsplit_kernel(const float* __restrict__ W, int ldw, int K, int N,
                              unsigned short* __restrict__ BThi,
                              unsigned short* __restrict__ BTlo,
                              int stride, int koff, int KPseg) {
    int k = blockIdx.x * 256 + threadIdx.x;
    int col = blockIdx.y;
    if (k >= KPseg) return;
    float v = (k < K && col < N) ? W[(size_t)k * ldw + col] : 0.f;
    unsigned short hi = f2bf(v);
    unsigned short lo = f2bf(v - bf2f(hi));
    BThi[(size_t)col * stride + koff + k] = hi;
    BTlo[(size_t)col * stride + koff + k] = lo;
}

__global__ void cvec_kernel(const float* __restrict__ b_feat,
                            const float* __restrict__ W0, float* __restrict__ cvec) {
    int j = threadIdx.x;
    float s = 0.f;
    for (int k = 0; k < 128; ++k) s += b_feat[k] * W0[(40 + k) * 128 + j];
    cvec[j] = s;
}

// ======== split-bf16 MFMA GEMM, LDS-staged, depth-1 register prefetch ========
// (R9 structure: best measured. VGPR ~64, 2 barriers / 32-K step.)
// ABF16=0: A f32 (dual-A concat along K), split hi/lo (3 MFMA products).
// ABF16=1: A1 bf16 [M][lda1] (2 products).
// NCT=4: BN=128 (wave w: rows (w&1)*32, cols (w>>1)*64).
// NCT=2: BN=64  (wave w: rows (w&1)*32, cols (w>>1)*32).
// ATTN (requires NCT=4): epilogue computes a_src/a_dst row dots, head = w>>1.
#define AHI 0
#define ALO 2048
#define BHI 4096
#define BLO 8192
template <int OUTBF16, int ABF16, int ATTN, int NCT>
__global__ __launch_bounds__(256) void mfma_gemm_kernel(
    const void* __restrict__ A1v, int lda1, int K1, int KP1,
    const float* __restrict__ A2, int lda2, int K2,
    int M,
    const unsigned short* __restrict__ BThi, const unsigned short* __restrict__ BTlo,
    int bstride, int KPtot,
    void* __restrict__ Cout, int ldc, int Nact, const float* __restrict__ bias,
    const float* __restrict__ att_src, const float* __restrict__ att_dst,
    float* __restrict__ a_srcO, float* __restrict__ a_dstO)
{
    __shared__ __align__(16) unsigned short lds[12288];
    const int t = threadIdx.x;
    const int w = t >> 6, lane = t & 63;
    const int row0 = blockIdx.x * 64;
    const int rbase = (w & 1) * 32;
    const int cbase = (NCT == 4) ? (w >> 1) * 64 : (w >> 1) * 32;

    f32x4 acc[2][NCT];
#pragma unroll
    for (int i = 0; i < 2; ++i)
#pragma unroll
        for (int j = 0; j < NCT; ++j) acc[i][j] = (f32x4){0.f, 0.f, 0.f, 0.f};

    const int arow = t >> 2;
    const int aslot = t & 3;
    const bool rowok = (row0 + arow) < M;
    const int aoff = arow * 32 + (((aslot ^ ((arow >> 1) & 3))) << 3);

    const int bc0 = t >> 2,         bs0 = t & 3;
    const int bc1 = (t + 256) >> 2, bs1 = (t + 256) & 3;
    const int bo0 = bc0 * 32 + ((bs0 ^ ((bc0 >> 1) & 3)) << 3);
    const int bo1 = bc1 * 32 + ((bs1 ^ ((bc1 >> 1) & 3)) << 3);

    float ra[8];
    short8_t rab;
    short8_t rbh0, rbl0, rbh1, rbl1;
    const short8_t zz = {0, 0, 0, 0, 0, 0, 0, 0};

#define LOADB_(k0_) {                                                     \
        size_t g0_ = (size_t)bc0 * bstride + (k0_) + bs0 * 8;             \
        rbh0 = *(const short8_t*)&BThi[g0_];                              \
        rbl0 = *(const short8_t*)&BTlo[g0_];                              \
        if (NCT == 4) {                                                   \
            size_t g1_ = (size_t)bc1 * bstride + (k0_) + bs1 * 8;         \
            rbh1 = *(const short8_t*)&BThi[g1_];                          \
            rbl1 = *(const short8_t*)&BTlo[g1_];                          \
        }                                                                 \
    }

#define LOADA_(k0_) {                                                     \
        if (ABF16) {                                                      \
            int gk = (k0_) + aslot * 8;                                   \
            if (rowok && gk + 8 <= K1) {                                  \
                const unsigned short* Ab =                                \
                    (const unsigned short*)A1v + (size_t)(row0 + arow) * lda1; \
                rab = *(const short8_t*)&Ab[gk];                          \
            } else rab = zz;                                              \
        } else {                                                          \
            const float* Asrc; int gk, Klim;                              \
            if ((k0_) < KP1) {                                            \
                Asrc = (const float*)A1v + (size_t)(row0 + arow) * lda1;  \
                gk = (k0_) + aslot * 8; Klim = K1;                        \
            } else {                                                      \
                Asrc = A2 + (size_t)(row0 + arow) * lda2;                 \
                gk = (k0_) - KP1 + aslot * 8; Klim = K2;                  \
            }                                                             \
            if (rowok && gk + 8 <= Klim) {                                \
                float4 v0 = *(const float4*)(Asrc + gk);                  \
                float4 v1 = *(const float4*)(Asrc + gk + 4);              \
                ra[0] = v0.x; ra[1] = v0.y; ra[2] = v0.z; ra[3] = v0.w;   \
                ra[4] = v1.x; ra[5] = v1.y; ra[6] = v1.z; ra[7] = v1.w;   \
            } else {                                                      \
                for (int j_ = 0; j_ < 8; ++j_) ra[j_] = 0.f;              \
            }                                                             \
        }                                                                 \
    }

    LOADA_(0);
    LOADB_(0);

    for (int k0 = 0; k0 < KPtot; k0 += 32) {
        // ---- write prefetched regs to LDS ----
        if (ABF16) {
            *(short8_t*)&lds[AHI + aoff] = rab;
        } else {
            short8_t vh, vl;
#pragma unroll
            for (int j = 0; j < 8; ++j) {
                unsigned short hi = f2bf(ra[j]);
                vh[j] = (short)hi;
                vl[j] = (short)f2bf(ra[j] - bf2f(hi));
            }
            *(short8_t*)&lds[AHI + aoff] = vh;
            *(short8_t*)&lds[ALO + aoff] = vl;
        }
        *(short8_t*)&lds[BHI + bo0] = rbh0;
        *(short8_t*)&lds[BLO + bo0] = rbl0;
        if (NCT == 4) {
            *(short8_t*)&lds[BHI + bo1] = rbh1;
            *(short8_t*)&lds[BLO + bo1] = rbl1;
        }
        __syncthreads();

        // ---- issue next tile's global loads (hidden under ds_reads + MFMA) ----
        if (k0 + 32 < KPtot) {
            LOADA_(k0 + 32);
            LOADB_(k0 + 32);
        }

        // ---- fragments + MFMA ----
        short8_t Ah[2], Al[2], Bh[NCT], Bl[NCT];
        const int fslot = lane >> 4;
#pragma unroll
        for (int rt = 0; rt < 2; ++rt) {
            int r = rbase + rt * 16 + (lane & 15);
            int off = r * 32 + ((fslot ^ ((r >> 1) & 3)) << 3);
            Ah[rt] = *(const short8_t*)&lds[AHI + off];
            if (!ABF16) Al[rt] = *(const short8_t*)&lds[ALO + off];
        }
#pragma unroll
        for (int ct = 0; ct < NCT; ++ct) {
            int c = cbase + ct * 16 + (lane & 15);
            int off = c * 32 + ((fslot ^ ((c >> 1) & 3)) << 3);
            Bh[ct] = *(const short8_t*)&lds[BHI + off];
            Bl[ct] = *(const short8_t*)&lds[BLO + off];
        }
#pragma unroll
        for (int rt = 0; rt < 2; ++rt)
#pragma unroll
            for (int ct = 0; ct < NCT; ++ct) {
                acc[rt][ct] = __builtin_amdgcn_mfma_f32_16x16x32_bf16(Ah[rt], Bh[ct], acc[rt][ct], 0, 0, 0);
                acc[rt][ct] = __builtin_amdgcn_mfma_f32_16x16x32_bf16(Ah[rt], Bl[ct], acc[rt][ct], 0, 0, 0);
                if (!ABF16)
                    acc[rt][ct] = __builtin_amdgcn_mfma_f32_16x16x32_bf16(Al[rt], Bh[ct], acc[rt][ct], 0, 0, 0);
            }
        __syncthreads();
    }

    // ---- epilogue ----
#pragma unroll
    for (int rt = 0; rt < 2; ++rt) {
#pragma unroll
        for (int reg = 0; reg < 4; ++reg) {
            int r = row0 + rbase + rt * 16 + (lane >> 4) * 4 + reg;
            if (ATTN) {
                float ps = 0.f, pd = 0.f;
#pragma unroll
                for (int ct = 0; ct < NCT; ++ct) {
                    int c = cbase + ct * 16 + (lane & 15);
                    ps += acc[rt][ct][reg] * att_src[c];
                    pd += acc[rt][ct][reg] * att_dst[c];
                }
#pragma unroll
                for (int off = 1; off < 16; off <<= 1) {
                    ps += __shfl_xor(ps, off);
                    pd += __shfl_xor(pd, off);
                }
                if (r < M && (lane & 15) == 0) {
                    int head = w >> 1;
                    a_srcO[r * 2 + head] = ps;
                    a_dstO[r * 2 + head] = pd;
                }
            }
            if (r >= M) continue;
#pragma unroll
            for (int ct = 0; ct < NCT; ++ct) {
                int c = cbase + ct * 16 + (lane & 15);
                float v = acc[rt][ct][reg];
                if (bias) v += bias[c];
                if (OUTBF16) {
                    ((unsigned short*)Cout)[(size_t)r * 128 + c] = f2bf(v);
                } else {
                    if (c < Nact)
                        ((float*)Cout)[(size_t)r * ldc + c] = v;
                }
            }
        }
    }
#undef LOADA_
#undef LOADB_
}

// ========== fused GAT aggregation: 2 nodes per wave, CSR gather ==========
template <int RELU, int OUTBF16>
__global__ __launch_bounds__(256) void gat_agg_fused(
    const int* __restrict__ row_ptr, const int* __restrict__ col,
    const float* __restrict__ a_src, const float* __restrict__ a_dst,
    const unsigned short* __restrict__ hb,
    const float* __restrict__ bias, void* __restrict__ out)
{
    int wv = (blockIdx.x * 256 + threadIdx.x) >> 6;
    int lane = threadIdx.x & 63;
    int hl = lane >> 5;
    int l5 = lane & 31;
    int n = wv * 2 + hl;
    if (n >= NN) return;   // NN even -> wave-uniform
    int hch = l5 >> 4;
    const uint2* h4 = (const uint2*)hb;

    float2 ad2 = ((const float2*)a_dst)[n];
    float adh = hch ? ad2.y : ad2.x;
    float2 as2 = ((const float2*)a_src)[n];
    float e0 = (hch ? as2.y : as2.x) + adh;
    e0 = e0 > 0.f ? e0 : 0.2f * e0;
    float w = __expf(e0);
    uint2 hv = h4[(size_t)n * 32 + l5];
    float a0 = w * u2f(hv.x << 16);
    float a1 = w * u2f(hv.x & 0xFFFF0000u);
    float a2 = w * u2f(hv.y << 16);
    float a3 = w * u2f(hv.y & 0xFFFF0000u);
    float den = w;

    int rs = row_ptr[n], re = row_ptr[n + 1];
    int deg = re - rs;
    int degO = __shfl(deg, lane ^ 32);
    int degm = deg > degO ? deg : degO;
    int nbm = (degm + 15) >> 4;

    for (int bi = 0; bi < nbm; ++bi) {
        int base = rs + bi * 16;
        int cnt = re - base;
        cnt = cnt < 0 ? 0 : (cnt > 16 ? 16 : cnt);
        int cntO = __shfl(cnt, lane ^ 32);
        int cntm = cnt > cntO ? cnt : cntO;
        int j16 = l5 & 15;
        int sL = 0;
        float wL = 0.f;
        if (j16 < cnt) {
            sL = col[base + j16];
            float2 as = ((const float2*)a_src)[sL];
            float tt = (hch ? as.y : as.x) + adh;
            tt = tt > 0.f ? tt : 0.2f * tt;
            wL = __expf(tt);
        }
        const int sb = hl << 5;
        const int wb = sb + (hch << 4);
        int i = 0;
        for (; i + 8 <= cntm; i += 8) {
            int s[8]; uint2 g[8]; float ws[8];
#pragma unroll
            for (int j = 0; j < 8; ++j) s[j] = __shfl(sL, sb + i + j);
#pragma unroll
            for (int j = 0; j < 8; ++j) g[j] = h4[(size_t)s[j] * 32 + l5];
#pragma unroll
            for (int j = 0; j < 8; ++j) ws[j] = __shfl(wL, wb + i + j);
#pragma unroll
            for (int j = 0; j < 8; ++j) {
                a0 += ws[j] * u2f(g[j].x << 16);
                a1 += ws[j] * u2f(g[j].x & 0xFFFF0000u);
                a2 += ws[j] * u2f(g[j].y << 16);
                a3 += ws[j] * u2f(g[j].y & 0xFFFF0000u);
                den += ws[j];
            }
        }
        for (; i + 4 <= cntm; i += 4) {
            int s[4]; uint2 g[4]; float ws[4];
#pragma unroll
            for (int j = 0; j < 4; ++j) s[j] = __shfl(sL, sb + i + j);
#pragma unroll
            for (int j = 0; j < 4; ++j) g[j] = h4[(size_t)s[j] * 32 + l5];
#pragma unroll
            for (int j = 0; j < 4; ++j) ws[j] = __shfl(wL, wb + i + j);
#pragma unroll
            for (int j = 0; j < 4; ++j) {
                a0 += ws[j] * u2f(g[j].x << 16);
                a1 += ws[j] * u2f(g[j].x & 0xFFFF0000u);
                a2 += ws[j] * u2f(g[j].y << 16);
                a3 += ws[j] * u2f(g[j].y & 0xFFFF0000u);
                den += ws[j];
            }
        }
        for (; i < cntm; ++i) {
            int s = __shfl(sL, sb + i);
            float ws = __shfl(wL, wb + i);
            uint2 g = h4[(size_t)s * 32 + l5];
            a0 += ws * u2f(g.x << 16);
            a1 += ws * u2f(g.x & 0xFFFF0000u);
            a2 += ws * u2f(g.y << 16);
            a3 += ws * u2f(g.y & 0xFFFF0000u);
            den += ws;
        }
    }
    float inv = 1.f / (den + 1e-16f);
    float4 b4 = ((const float4*)bias)[l5];
    float o0 = a0 * inv + b4.x;
    float o1 = a1 * inv + b4.y;
    float o2 = a2 * inv + b4.z;
    float o3 = a3 * inv + b4.w;
    if (RELU) {
        o0 = fmaxf(o0, 0.f); o1 = fmaxf(o1, 0.f);
        o2 = fmaxf(o2, 0.f); o3 = fmaxf(o3, 0.f);
    }
    if (OUTBF16) {
        uint2 pk;
        pk.x = (unsigned int)f2bf(o0) | ((unsigned int)f2bf(o1) << 16);
        pk.y = (unsigned int)f2bf(o2) | ((unsigned int)f2bf(o3) << 16);
        ((uint2*)out)[(size_t)n * 32 + l5] = pk;
    } else {
        ((float4*)out)[(size_t)n * 32 + l5] = make_float4(o0, o1, o2, o3);
    }
}

extern "C" void kernel_launch(void* const* d_in, const int* in_sizes, int n_in,
                              void* d_out, int out_size, void* d_ws, size_t ws_size,
                              hipStream_t stream) {
    const float* logits   = (const float*)d_in[0];
    const float* features = (const float*)d_in[1];
    const int*   ei       = (const int*)d_in[2];
    const float* W_feat   = (const float*)d_in[3];
    const float* b_feat   = (const float*)d_in[4];
    const float* W0       = (const float*)d_in[5];
    const float* att_src0 = (const float*)d_in[6];
    const float* att_dst0 = (const float*)d_in[7];
    const float* bias0    = (const float*)d_in[8];
    const float* W1       = (const float*)d_in[9];
    const float* att_src1 = (const float*)d_in[10];
    const float* att_dst1 = (const float*)d_in[11];
    const float* bias1    = (const float*)d_in[12];
    const float* W_out    = (const float*)d_in[13];
    const float* b_out    = (const float*)d_in[14];
    float* out = (float*)d_out;

    float* agg    = (float*)d_ws;                       // NN*128 f32 (bf16 view for L0)
    float* a_srcb = agg + (size_t)NN * 128;             // NN*2
    float* a_dstb = a_srcb + (size_t)NN * 2;            // NN*2
    float* Wc     = a_dstb + (size_t)NN * 2;            // 256*128
    float* cvec   = Wc + 256 * 128;                     // 128
    unsigned short* hbuf = (unsigned short*)(cvec + 128);      // NN*128 bf16
    unsigned short* BT0hi = hbuf + (size_t)NN * 128;    // 128*320
    unsigned short* BT0lo = BT0hi + 128 * 320;
    unsigned short* BTbhi = BT0lo + 128 * 320;          // 128*128 (W0b planes)
    unsigned short* BTblo = BTbhi + 128 * 128;
    unsigned short* BT1hi = BTblo + 128 * 128;          // 128*128
    unsigned short* BT1lo = BT1hi + 128 * 128;
    unsigned short* BTohi = BT1lo + 128 * 128;          // 128*128
    unsigned short* BTolo = BTohi + 128 * 128;
    int* row_ptr = (int*)(BTolo + 128 * 128);           // NN+1
    int* colbuf  = row_ptr + NN + 1;                    // EE
    int* cnt     = colbuf + EE;                         // NPBLK*NBUCK
    int* pbase   = cnt + NPBLK * NBUCK;                 // NPBLK*NBUCK
    int* bbase   = pbase + NPBLK * NBUCK;               // NBUCK+1
    unsigned int* bbuf = (unsigned int*)agg;            // EE u32, aliases agg
    unsigned short* aggb = (unsigned short*)agg;        // bf16 view for layer0 output

    dim3 blk(256);
    const int gemmGrid = (NN + 63) / 64;
    const int aggGrid = (NN / 2 + 3) / 4;

    // ---- CSR build ----
    part_count<<<dim3(NPBLK), blk, 0, stream>>>(ei, cnt);
    part_scan<<<dim3(1), dim3(512), 0, stream>>>(cnt, pbase, bbase);
    part_scatter<<<dim3(NPBLK), blk, 0, stream>>>(ei, pbase, bbuf);
    csr_build<<<dim3(NBUCK), blk, 0, stream>>>(bbuf, bbase, row_ptr, colbuf);

    // ---- weight prep ----
    bsplit_kernel<<<dim3(1, 128), blk, 0, stream>>>(W0, 128, 40, 128, BT0hi, BT0lo, 320, 0, 64);
    bsplit_kernel<<<dim3(1, 128), blk, 0, stream>>>(W0 + 40 * 128, 128, 128, 128, BTbhi, BTblo, 128, 0, 128);
    mfma_gemm_kernel<0, 0, 0, 4><<<dim3(4), blk, 0, stream>>>(
        W_feat, 128, 128, 128, nullptr, 0, 0, 256,
        BTbhi, BTblo, 128, 128, Wc, 128, 128, nullptr,
        nullptr, nullptr, nullptr, nullptr);
    cvec_kernel<<<dim3(1), dim3(128), 0, stream>>>(b_feat, W0, cvec);
    bsplit_kernel<<<dim3(1, 128), blk, 0, stream>>>(Wc, 128, 256, 128, BT0hi, BT0lo, 320, 64, 256);
    bsplit_kernel<<<dim3(1, 128), blk, 0, stream>>>(W1, 128, 128, 128, BT1hi, BT1lo, 128, 0, 128);
    bsplit_kernel<<<dim3(1, 128), blk, 0, stream>>>(W_out, 40, 128, 40, BTohi, BTolo, 128, 0, 128);

    // ---- GAT layer 0: h0 = logits@W0a + features@Wc + cvec (attn dots fused) ----
    mfma_gemm_kernel<1, 0, 1, 4><<<dim3(gemmGrid), blk, 0, stream>>>(
        logits, 40, 40, 64, features, 256, 256, NN,
        BT0hi, BT0lo, 320, 320, hbuf, 128, 128, cvec,
        att_src0, att_dst0, a_srcb, a_dstb);
    gat_agg_fused<1, 1><<<dim3(aggGrid), blk, 0, stream>>>(
        row_ptr, colbuf, a_srcb, a_dstb, hbuf, bias0, aggb);

    // ---- GAT layer 1 (bf16 A, attn dots fused) ----
    mfma_gemm_kernel<1, 1, 1, 4><<<dim3(gemmGrid), blk, 0, stream>>>(
        aggb, 128, 128, 128, nullptr, 0, 0, NN,
        BT1hi, BT1lo, 128, 128, hbuf, 128, 128, nullptr,
        att_src1, att_dst1, a_srcb, a_dstb);
    gat_agg_fused<0, 0><<<dim3(aggGrid), blk, 0, stream>>>(
        row_ptr, colbuf, a_srcb, a_dstb, hbuf, bias1, agg);

    // ---- output projection (BN=64, 40 used) ----
    mfma_gemm_kernel<0, 0, 0, 2><<<dim3(gemmGrid), blk, 0, stream>>>(
        agg, 128, 128, 128, nullptr, 0, 0, NN,
        BTohi, BTolo, 128, 128, out, 40, 40, b_out,
        nullptr, nullptr, nullptr, nullptr);
}